// Round 13
// baseline (87.181 us; speedup 1.0000x reference)
//
#include <hip/hip_runtime.h>

// Problem constants (from reference setup_inputs)
constexpr int cB = 32, cC = 6, cT = 64;
constexpr int cK = 8, cN = 128;
constexpr int cS = 32, cP = 64;
constexpr int NCL = cS * cP;          // 2048 centerline points per batch
constexpr int G = 4;                  // blocks per (b,c); 16 points per block
constexpr int PPW = 4;                // points per wave (register-blocked)
constexpr int NIT = 16;               // 1024 slots / 64 lanes
constexpr int GRP = 4;                // iterations per staging group (MLP=4)
constexpr float F_EPS = 1e-6f;
constexpr float F_THRESHOLD = 0.5f;

// 768 blocks (3/CU), 4 waves/block, 4 pts/wave. Each pass stages table data
// in GROUPS of 4 iterations (ping-pong buffers, <=32 VGPR live) so 4-12
// loads are always in flight -> memory latency amortized 4x vs the 1-deep
// loop-carried chain of R5-R11. R12 tried all-16-at-once and SPILLED
// (WRITE_SIZE 17MB, VGPR=84); this version keeps peak pressure ~100 VGPR.
// No shuffles in hot loops: both segment vertices loaded directly (pad slot
// s%128==127 clamps e:=a -> d=0 endpoint distance, min-neutral, hit-masked).
__global__ __launch_bounds__(256, 3) void offroad_kernel(
    const float* __restrict__ points,         // (B, C, T, 2)
    const float* __restrict__ road_boundary,  // (B, K, N, 2)
    const float* __restrict__ centerlines,    // (B, S, P, 2)
    float* __restrict__ out)                  // (B, C), pre-zeroed
{
    const int blk  = blockIdx.x;         // 0 .. B*C*G-1
    const int g    = blk & (G - 1);
    const int bc   = blk >> 2;           // b*C + c
    const int b    = bc / cC;
    const int lane = threadIdx.x & 63;
    const int wave = threadIdx.x >> 6;

    const float2* __restrict__ rb2 =
        (const float2*)(road_boundary + (size_t)b * cK * cN * 2);
    const float4* __restrict__ cl4 =
        (const float4*)(centerlines + (size_t)b * NCL * 2);
    const float2* __restrict__ cl2 = (const float2*)cl4;

    // 4 consecutive points for this wave
    const int t0 = (g << 4) | (wave << 2);   // in [0, 64)
    const float* pb = points + (((size_t)bc) * cT + t0) * 2;
    float px[PPW], py[PPW];
    #pragma unroll
    for (int p = 0; p < PPW; ++p) { px[p] = pb[2 * p]; py[p] = pb[2 * p + 1]; }

    // ---- Pass 1: centerline argmin, group-staged (MLP=4) ----
    float best_d2[PPW];
    int   best_i[PPW];
    #pragma unroll
    for (int p = 0; p < PPW; ++p) { best_d2[p] = 3.4e38f; best_i[p] = 0x7fffffff; }

    {
        float4 buf[2][GRP];
        #pragma unroll
        for (int j = 0; j < GRP; ++j) buf[0][j] = cl4[lane + 64 * j];

        #pragma unroll
        for (int grp = 0; grp < NIT / GRP; ++grp) {
            const int cur = grp & 1;
            if (grp < NIT / GRP - 1) {
                #pragma unroll
                for (int j = 0; j < GRP; ++j)
                    buf[cur ^ 1][j] = cl4[lane + 64 * (GRP * (grp + 1) + j)];
            }
            #pragma unroll
            for (int j = 0; j < GRP; ++j) {
                const float4 cp = buf[cur][j];
                const int ia = 2 * (lane + 64 * (GRP * grp + j));
                #pragma unroll
                for (int p = 0; p < PPW; ++p) {
                    float dxa = px[p] - cp.x, dya = py[p] - cp.y;
                    float d2a = dxa * dxa + dya * dya;
                    float dxb = px[p] - cp.z, dyb = py[p] - cp.w;
                    float d2b = dxb * dxb + dyb * dyb;
                    float dmin = d2a; int imin = ia;
                    if (d2b < d2a) { dmin = d2b; imin = ia + 1; } // low idx tie
                    // per-lane indices ascend: strict < keeps first index
                    if (dmin < best_d2[p] ||
                        (dmin == best_d2[p] && imin < best_i[p])) {
                        best_d2[p] = dmin; best_i[p] = imin;
                    }
                }
            }
        }
    }
    // argmin butterfly across 64 lanes (tie -> lower index)
    #pragma unroll
    for (int off = 1; off <= 32; off <<= 1) {
        #pragma unroll
        for (int p = 0; p < PPW; ++p) {
            float od2 = __shfl_xor(best_d2[p], off);
            int   oi  = __shfl_xor(best_i[p], off);
            if (od2 < best_d2[p] || (od2 == best_d2[p] && oi < best_i[p])) {
                best_d2[p] = od2; best_i[p] = oi;
            }
        }
    }
    // closest centerline point per point (4 broadcast loads, one round)
    float dax[PPW], day[PPW];
    #pragma unroll
    for (int p = 0; p < PPW; ++p) {
        float2 cc = cl2[best_i[p]];
        dax[p] = cc.x - px[p]; day[p] = cc.y - py[p];   // da = a2 - a1
    }

    // ---- Pass 2: segment distance + intersection, group-staged ----
    float min_d2[PPW];
    int   hit[PPW];
    #pragma unroll
    for (int p = 0; p < PPW; ++p) { min_d2[p] = 3.4e38f; hit[p] = 0; }

    {
        float2 A[2][GRP], E[2][GRP];
        #pragma unroll
        for (int j = 0; j < GRP; ++j) {
            const int s = lane + 64 * j;
            const int v = ((s & (cN - 1)) < cN - 1) ? 1 : 0;
            A[0][j] = rb2[s];
            E[0][j] = rb2[s + v];
        }

        #pragma unroll
        for (int grp = 0; grp < NIT / GRP; ++grp) {
            const int cur = grp & 1;
            if (grp < NIT / GRP - 1) {
                #pragma unroll
                for (int j = 0; j < GRP; ++j) {
                    const int s = lane + 64 * (GRP * (grp + 1) + j);
                    const int v = ((s & (cN - 1)) < cN - 1) ? 1 : 0;
                    A[cur ^ 1][j] = rb2[s];
                    E[cur ^ 1][j] = rb2[s + v];
                }
            }
            #pragma unroll
            for (int j = 0; j < GRP; ++j) {
                const int s = lane + 64 * (GRP * grp + j);
                const int valid = ((s & (cN - 1)) < cN - 1) ? 1 : 0;
                const float2 a = A[cur][j];
                const float2 e = E[cur][j];
                const float dx = e.x - a.x, dy = e.y - a.y;
                const float inv_e2 =
                    __builtin_amdgcn_rcpf(dx * dx + dy * dy + F_EPS);

                #pragma unroll
                for (int p = 0; p < PPW; ++p) {
                    // shared: v1 = p - a (== reference's dp = a1 - b1)
                    float v1x = px[p] - a.x, v1y = py[p] - a.y;
                    // point-to-segment distance (pad: d=0 -> endpoint dist,
                    // >= adjacent real segment -> min unaffected)
                    float proj = (v1x * dx + v1y * dy) * inv_e2;
                    proj = __builtin_amdgcn_fmed3f(proj, 0.0f, 1.0f);
                    float ex = v1x - dx * proj;
                    float ey = v1y - dy * proj;
                    min_d2[p] = fminf(min_d2[p], ex * ex + ey * ey);
                    // intersection, division-free (w = cross(da,db)+EPS):
                    //   t,u in [0,1] <=> ct*w in [0,w^2] and cu*w in [0,w^2]
                    float w  = dax[p] * dy - day[p] * dx + F_EPS;
                    float w2 = w * w;
                    float ct = (dax[p] * v1y - day[p] * v1x) * w;
                    float cu = (dx * v1y - dy * v1x) * w;
                    bool inb = (ct >= 0.0f) & (ct <= w2) &
                               (cu >= 0.0f) & (cu <= w2);
                    hit[p] |= valid & (int)inb;
                }
            }
        }
    }

    // ---- reduce min_d2 / hit across 64 lanes ----
    #pragma unroll
    for (int off = 1; off <= 32; off <<= 1) {
        #pragma unroll
        for (int p = 0; p < PPW; ++p) {
            min_d2[p] = fminf(min_d2[p], __shfl_xor(min_d2[p], off));
            hit[p]   |= __shfl_xor(hit[p], off);
        }
    }

    // ---- final loss for this wave's 4 points, one atomic per wave ----
    float total = 0.0f;
    #pragma unroll
    for (int p = 0; p < PPW; ++p) {
        float md = sqrtf(min_d2[p]);
        float sd = hit[p] ? md : -md;               // inside -> negative
        total += fmaxf(sd + F_THRESHOLD, 0.0f);
    }
    if (lane == 0)
        atomicAdd(&out[bc], total);
}

extern "C" void kernel_launch(void* const* d_in, const int* in_sizes, int n_in,
                              void* d_out, int out_size, void* d_ws, size_t ws_size,
                              hipStream_t stream) {
    const float* points      = (const float*)d_in[0];
    const float* boundary    = (const float*)d_in[1];
    const float* centerlines = (const float*)d_in[2];
    float* out = (float*)d_out;
    hipMemsetAsync(out, 0, (size_t)out_size * sizeof(float), stream);
    offroad_kernel<<<cB * cC * G, 256, 0, stream>>>(points, boundary, centerlines, out);
}